// Round 20
// baseline (179.894 us; speedup 1.0000x reference)
//
#include <hip/hip_runtime.h>
#include <hip/hip_bf16.h>
#include <stdint.h>

// Problem constants (fixed by setup_inputs)
#define B_   64
#define H_   512
#define W_   512
#define S_N  1024      // n_segments
#define E_N  768       // embed_dim
#define K_N  768       // C*box*box = 3*16*16
#define HALF 8

typedef short bf16x8 __attribute__((ext_vector_type(8)));
typedef float f32x4  __attribute__((ext_vector_type(4)));
typedef float f32x4u __attribute__((ext_vector_type(4), aligned(4)));  // 4B-aligned float4

__device__ __forceinline__ unsigned short f2bf(float f) {
  union { float f; unsigned u; } v; v.f = f;
  unsigned u = v.u;
  u += 0x7FFF + ((u >> 16) & 1);   // RNE
  return (unsigned short)(u >> 16);
}

// ------ Phase 1 (merged): per-(b,s) packed sums (blocks 0..1023) +
//        conv_w fp32->bf16 (blocks 1024..1599) ---------------------------------
__global__ void k_accum_convw(const int* __restrict__ seg,
                              unsigned long long* __restrict__ partials,
                              const float* __restrict__ w,
                              unsigned short* __restrict__ wb) {
  __shared__ unsigned long long ls[S_N];
  const int bid = blockIdx.x;
  const int tid = threadIdx.x;
  if (bid >= 1024) {                 // conv_w conversion: 147,456 float4s
    int idx = (bid - 1024) * 256 + tid;
    float4 v = ((const float4*)w)[idx];
    ushort4 o;
    o.x = f2bf(v.x); o.y = f2bf(v.y); o.z = f2bf(v.z); o.w = f2bf(v.w);
    ((ushort4*)wb)[idx] = o;
    return;
  }
  const int xblk = bid & 15;         // 0..15
  const int b    = bid >> 4;         // 0..63
  for (int i = tid; i < S_N; i += 256) ls[i] = 0ULL;
  __syncthreads();
  const int pix0 = xblk * 16384;
  const int4* segb = (const int4*)(seg + (size_t)b * (H_ * W_) + pix0);
  for (int it = 0; it < 16; ++it) {
    int4 s4 = segb[it * 256 + tid];
    int p0 = pix0 + (it * 256 + tid) * 4;
    unsigned long long base = ((unsigned long long)(unsigned)(p0 >> 9) << 39)
                            | ((unsigned long long)(unsigned)(p0 & (W_ - 1)) << 15)
                            | 1ULL;
    #pragma unroll
    for (int j = 0; j < 4; ++j) {
      int s = (&s4.x)[j];
      s = ((unsigned)s < S_N) ? s : 0;
      atomicAdd(&ls[s], base + ((unsigned long long)j << 15));
    }
  }
  __syncthreads();
  unsigned long long* gp = partials + ((size_t)b * 16 + xblk) * S_N;
  for (int s = tid; s < S_N; s += 256) gp[s] = ls[s];
}

// ------ Phase 2: FUSED gather-GEMM, 128x128 tile, 3 blocks/CU (TLP regime) ----
// r18/r19 synthesis: registers (acc=128 AGPR), not LDS, pinned every prior
// variant at 2 waves/SIMD = ONE block/CU -> all barrier/stage stalls exposed
// (the universal ~115us ceiling). This kernel enters the untested regime:
// acc[4][4]=64 AGPR + ~95 VGPR (~160 total, launch_bounds(256,3) caps 170)
// -> 3 waves/SIMD; LDS 33KB -> 3 co-resident 4-wave blocks per CU = 12
// independent waves. No software pipelining: simple r10 loop {sync; stageB;
// gatherA; drain; sync; MFMA} — co-resident blocks fill each other's stalls
// (m114). Same verified T2 both-sides swizzle; same coalesced fused gather.
__global__ __launch_bounds__(256, 3) void k_gemmfg4(
    const float* __restrict__ img,
    const unsigned long long* __restrict__ partials,
    const unsigned short* __restrict__ Bmat,
    float* __restrict__ out) {
  __shared__ unsigned short As[128 * 64];   // 16 KB
  __shared__ unsigned short Bs[128 * 64];   // 16 KB
  __shared__ int2 pc[128];
  const int tid  = threadIdx.x;
  const int wave = tid >> 6;         // 0..3
  const int lane = tid & 63;

  // bijective XCD remap: 3072 blocks = 8 XCDs x 384; bn fastest
  const int virt = (blockIdx.x & 7) * 384 + (blockIdx.x >> 3);
  const int bm = virt / 6;           // 0..511
  const int bn = virt - bm * 6;      // 0..5
  const int gm0 = bm * 128;
  const int gn0 = bn * 128;
  const int b   = bm >> 3;           // batch (128 rows per block, 1024 per batch)
  const float* ib = img + (size_t)b * 3 * H_ * W_;

  // ---- one-time: coords for this block's 128 patches ----
  if (tid < 128) {
    const int s = (gm0 + tid) & (S_N - 1);
    unsigned c = 0, sx = 0, sy = 0;
    #pragma unroll
    for (int x = 0; x < 16; ++x) {
      unsigned long long v = partials[((size_t)b * 16 + x) * S_N + s];
      c  += (unsigned)(v & 0x7FFFULL);
      sx += (unsigned)((v >> 15) & 0xFFFFFFULL);
      sy += (unsigned)(v >> 39);
    }
    int xmin = 0, ymin = 0;
    if (c > 0) {
      float cf = (float)c;
      xmin = (int)floorf((float)sx / cf);   // IEEE f32 div of exact ints == ref
      ymin = (int)floorf((float)sy / cf);
    }
    pc[tid] = make_int2(xmin - HALF, ymin - HALF);
  }

  const int wr = wave >> 1;          // 0..1
  const int wc = wave & 1;           // 0..1
  const int rlo  = lane & 15;
  const int rsel = lane & 7;
  const int sub  = lane >> 4;        // 0..3
  int swz[2];
  swz[0] = ((0 + sub) ^ rsel) * 8;
  swz[1] = ((4 + sub) ^ rsel) * 8;

  f32x4 acc[4][4];
  #pragma unroll
  for (int i = 0; i < 4; ++i)
    #pragma unroll
    for (int j = 0; j < 4; ++j)
      acc[i][j] = (f32x4){0.f, 0.f, 0.f, 0.f};

  __syncthreads();                   // pc ready

  // ---- loop-invariant gather context: 4 rows/thread (32 apart), chunk c0 ----
  const int c0 = tid & 7;
  const int rr = tid >> 3;           // 0..31
  int2 pi[4]; bool inti[4];
  const float* arow[4];
  #pragma unroll
  for (int i = 0; i < 4; ++i) {
    int row = i * 32 + rr;
    int2 p = pc[row];
    pi[i] = p;
    inti[i] = (p.x >= 0 && p.x <= W_ - 16 && p.y >= 0 && p.y <= H_ - 16);
    arow[i] = ib + (size_t)(inti[i] ? p.y : 0) * W_ + (inti[i] ? p.x : 0);
  }

  for (int kt = 0; kt < 12; ++kt) {
    const int k0 = kt * 64;

    // B stage: 4 global_load_lds/thread (T2 pre-swizzled source, linear dest)
    #pragma unroll
    for (int i = 0; i < 4; ++i) {
      int seg = i * 256 + tid;
      int row = seg >> 3;
      int csrc = (seg & 7) ^ (row & 7);
      const unsigned short* g = Bmat + (size_t)(gn0 + row) * K_N + k0 + csrc * 8;
      __builtin_amdgcn_global_load_lds((const __attribute__((address_space(1))) void*)g,
        (__attribute__((address_space(3))) void*)&Bs[(i * 256 + wave * 64) * 8], 16, 0, 0);
    }

    // A gather (coalesced: 8 lanes = 1 patch row-window), cvt, swizzled write
    {
      const int k  = k0 + c0 * 8;
      const int ch = k >> 8, hh = (k >> 4) & 15, w0 = k & 15;
      const int roff = ((ch << 9) + hh) * W_ + w0;
      #pragma unroll
      for (int i = 0; i < 4; ++i) {
        int row = i * 32 + rr;
        f32x4 lo, hi;
        if (inti[i]) {
          const float* rp = arow[i] + roff;
          lo = *(const f32x4u*)rp;
          hi = *(const f32x4u*)(rp + 4);
        } else {                     // rare edge patch: masked scalar
          int y = pi[i].y + hh;
          int x0 = pi[i].x + w0;
          bool yok = (unsigned)y < H_;
          const float* rp = ib + (size_t)((ch << 9) + (yok ? y : 0)) * W_;
          #pragma unroll
          for (int j = 0; j < 4; ++j) {
            int x = x0 + j;
            lo[j] = (yok && (unsigned)x < W_) ? rp[x] : 0.f;
          }
          #pragma unroll
          for (int j = 0; j < 4; ++j) {
            int x = x0 + 4 + j;
            hi[j] = (yok && (unsigned)x < W_) ? rp[x] : 0.f;
          }
        }
        bf16x8 t;
        #pragma unroll
        for (int j = 0; j < 4; ++j) {
          t[j]     = (short)f2bf(lo[j]);
          t[4 + j] = (short)f2bf(hi[j]);
        }
        *(bf16x8*)&As[row * 64 + ((c0 ^ (row & 7)) << 3)] = t;
      }
    }

    asm volatile("s_waitcnt vmcnt(0) lgkmcnt(0)" ::: "memory");  // B landed, A writes done
    __syncthreads();                                             // tile visible

    #pragma unroll
    for (int kk = 0; kk < 2; ++kk) {
      bf16x8 av[4], bv[4];
      #pragma unroll
      for (int mi = 0; mi < 4; ++mi)
        av[mi] = *(const bf16x8*)&As[(wr * 64 + mi * 16 + rlo) * 64 + swz[kk]];
      #pragma unroll
      for (int ni = 0; ni < 4; ++ni)
        bv[ni] = *(const bf16x8*)&Bs[(wc * 64 + ni * 16 + rlo) * 64 + swz[kk]];
      __builtin_amdgcn_s_setprio(1);
      #pragma unroll
      for (int mi = 0; mi < 4; ++mi)
        #pragma unroll
        for (int ni = 0; ni < 4; ++ni)
          acc[mi][ni] = __builtin_amdgcn_mfma_f32_16x16x32_bf16(
              av[mi], bv[ni], acc[mi][ni], 0, 0, 0);
      __builtin_amdgcn_s_setprio(0);
    }

    __syncthreads();                 // all reads done before next tile's writes
  }

  // Epilogue: C/D layout col=lane&15, row=(lane>>4)*4+reg
  const int row0 = gm0 + wr * 64 + (lane >> 4) * 4;
  const int col0 = gn0 + wc * 64 + (lane & 15);
  #pragma unroll
  for (int mi = 0; mi < 4; ++mi)
    #pragma unroll
    for (int ni = 0; ni < 4; ++ni)
      #pragma unroll
      for (int r = 0; r < 4; ++r)
        out[(size_t)(row0 + mi * 16 + r) * E_N + (col0 + ni * 16)] = acc[mi][ni][r];
}

extern "C" void kernel_launch(void* const* d_in, const int* in_sizes, int n_in,
                              void* d_out, int out_size, void* d_ws, size_t ws_size,
                              hipStream_t stream) {
  const float* img = (const float*)d_in[0];
  const int*   seg = (const int*)d_in[1];
  const float* cw  = (const float*)d_in[2];
  float* out = (float*)d_out;
  char* ws = (char*)d_ws;

  unsigned long long* partials = (unsigned long long*)ws;    // 8,388,608 B
  unsigned short* Bmat = (unsigned short*)(ws + 8388608);    // 1,179,648 B

  k_accum_convw<<<1600, 256, 0, stream>>>(seg, partials, cw, Bmat);
  k_gemmfg4<<<3072, 256, 0, stream>>>(img, partials, Bmat, out);
}

// Round 21
// 167.807 us; speedup vs baseline: 1.0720x; 1.0720x over previous
//
#include <hip/hip_runtime.h>
#include <hip/hip_bf16.h>
#include <stdint.h>

// Problem constants (fixed by setup_inputs)
#define B_   64
#define H_   512
#define W_   512
#define S_N  1024      // n_segments
#define E_N  768       // embed_dim
#define K_N  768       // C*box*box = 3*16*16
#define HALF 8

typedef short bf16x8 __attribute__((ext_vector_type(8)));
typedef float f32x4  __attribute__((ext_vector_type(4)));
typedef float f32x4u __attribute__((ext_vector_type(4), aligned(4)));  // 4B-aligned float4

__device__ __forceinline__ unsigned short f2bf(float f) {
  union { float f; unsigned u; } v; v.f = f;
  unsigned u = v.u;
  u += 0x7FFF + ((u >> 16) & 1);   // RNE
  return (unsigned short)(u >> 16);
}

// ------ Phase 1 (merged): per-(b,s) packed sums (blocks 0..1023) +
//        conv_w fp32->bf16 (blocks 1024..1599) ---------------------------------
__global__ void k_accum_convw(const int* __restrict__ seg,
                              unsigned long long* __restrict__ partials,
                              const float* __restrict__ w,
                              unsigned short* __restrict__ wb) {
  __shared__ unsigned long long ls[S_N];
  const int bid = blockIdx.x;
  const int tid = threadIdx.x;
  if (bid >= 1024) {                 // conv_w conversion: 147,456 float4s
    int idx = (bid - 1024) * 256 + tid;
    float4 v = ((const float4*)w)[idx];
    ushort4 o;
    o.x = f2bf(v.x); o.y = f2bf(v.y); o.z = f2bf(v.z); o.w = f2bf(v.w);
    ((ushort4*)wb)[idx] = o;
    return;
  }
  const int xblk = bid & 15;         // 0..15
  const int b    = bid >> 4;         // 0..63
  for (int i = tid; i < S_N; i += 256) ls[i] = 0ULL;
  __syncthreads();
  const int pix0 = xblk * 16384;
  const int4* segb = (const int4*)(seg + (size_t)b * (H_ * W_) + pix0);
  for (int it = 0; it < 16; ++it) {
    int4 s4 = segb[it * 256 + tid];
    int p0 = pix0 + (it * 256 + tid) * 4;
    unsigned long long base = ((unsigned long long)(unsigned)(p0 >> 9) << 39)
                            | ((unsigned long long)(unsigned)(p0 & (W_ - 1)) << 15)
                            | 1ULL;
    #pragma unroll
    for (int j = 0; j < 4; ++j) {
      int s = (&s4.x)[j];
      s = ((unsigned)s < S_N) ? s : 0;
      atomicAdd(&ls[s], base + ((unsigned long long)j << 15));
    }
  }
  __syncthreads();
  unsigned long long* gp = partials + ((size_t)b * 16 + xblk) * S_N;
  for (int s = tid; s < S_N; s += 256) gp[s] = ls[s];
}

// ------ Phase 2: PERSISTENT fused gather-GEMM (r19 core, bm pinned, bn loop) --
// r19's gemmfg3 (proven: 141us total, FETCH 21MB) ran 768 blocks = 3 turnover
// rounds at 1 block/CU. r14's persistent attempt failed on Amat L2 thrash
// (FETCH 213MB) — but the FUSED kernel's A source is img's center (~2.5MB/XCD,
// L2-resident), so that failure mode is gone. Grid 256 (1/CU), bm pinned,
// bn=t*256 loops inside: zero turnover, pc + gather context computed once
// (was 3x), epilogue stores overlap next t's prologue (register-only reads,
// no barrier needed between them). K-loop machinery is r19-verbatim.
__global__ __launch_bounds__(512) void k_gemmfg3p(
    const float* __restrict__ img,
    const unsigned long long* __restrict__ partials,
    const unsigned short* __restrict__ Bmat,
    float* __restrict__ out) {
  __shared__ unsigned short As[2][256 * 64];   // 2 x 32 KB
  __shared__ unsigned short Bs[2][256 * 64];   // 2 x 32 KB
  __shared__ int2 pc[256];
  const int tid  = threadIdx.x;
  const int wave = tid >> 6;
  const int lane = tid & 63;

  // bijective XCD remap: 256 blocks = 8 XCDs x 32; bm pinned per block
  const int bm = (blockIdx.x & 7) * 32 + (blockIdx.x >> 3);   // 0..255
  const int gm0 = bm * 256;
  int gn0 = 0;                        // set per t; lambdas capture by ref
  const int b   = bm >> 2;
  const float* ib = img + (size_t)b * 3 * H_ * W_;

  // ---- one-time: coords for this block's 256 patches ----
  if (tid < 256) {
    const int s = (gm0 + tid) & (S_N - 1);
    unsigned c = 0, sx = 0, sy = 0;
    #pragma unroll
    for (int x = 0; x < 16; ++x) {
      unsigned long long v = partials[((size_t)b * 16 + x) * S_N + s];
      c  += (unsigned)(v & 0x7FFFULL);
      sx += (unsigned)((v >> 15) & 0xFFFFFFULL);
      sy += (unsigned)(v >> 39);
    }
    int xmin = 0, ymin = 0;
    if (c > 0) {
      float cf = (float)c;
      xmin = (int)floorf((float)sx / cf);   // IEEE f32 div of exact ints == ref
      ymin = (int)floorf((float)sy / cf);
    }
    pc[tid] = make_int2(xmin - HALF, ymin - HALF);
  }

  const int wr = wave >> 2;          // 0..1
  const int wc = wave & 3;           // 0..3
  const int rlo  = lane & 15;
  const int rsel = lane & 7;
  const int sub  = lane >> 4;
  int swz[2];
  swz[0] = ((0 + sub) ^ rsel) * 8;
  swz[1] = ((4 + sub) ^ rsel) * 8;

  f32x4 acc[8][4];
  #pragma unroll
  for (int i = 0; i < 8; ++i)
    #pragma unroll
    for (int j = 0; j < 4; ++j)
      acc[i][j] = (f32x4){0.f, 0.f, 0.f, 0.f};

  __syncthreads();                   // pc ready

  // ---- loop-invariant A-gather context: 2 rows/thread, 4 threads/row ----
  const int cd = tid & 3;
  const int r0 = tid >> 2;           // rows r0 and 128+r0
  int2 pi[2]; bool inti[2];
  const float* arow[2];
  #pragma unroll
  for (int i = 0; i < 2; ++i) {
    int row = i * 128 + r0;
    int2 p = pc[row];
    pi[i] = p;
    inti[i] = (p.x >= 0 && p.x <= W_ - 16 && p.y >= 0 && p.y <= H_ - 16);
    arow[i] = ib + (size_t)(inti[i] ? p.y : 0) * W_ + (inti[i] ? p.x : 0);
  }

  f32x4 ga[2][2];                    // 16 VGPRs live across one MFMA sub-phase

  auto issueA = [&](int k0, int h) {
    const int c  = h * 4 + cd;
    const int k  = k0 + c * 8;
    const int ch = k >> 8, hh = (k >> 4) & 15, w0 = k & 15;
    const int roff = ((ch << 9) + hh) * W_ + w0;
    #pragma unroll
    for (int i = 0; i < 2; ++i) {
      if (inti[i]) {
        const float* rp = arow[i] + roff;
        ga[i][0] = *(const f32x4u*)rp;
        ga[i][1] = *(const f32x4u*)(rp + 4);
      } else {
        int y = pi[i].y + hh;
        int x0 = pi[i].x + w0;
        bool yok = (unsigned)y < H_;
        const float* rp = ib + (size_t)((ch << 9) + (yok ? y : 0)) * W_;
        #pragma unroll
        for (int j = 0; j < 4; ++j) {
          int x = x0 + j;
          ga[i][0][j] = (yok && (unsigned)x < W_) ? rp[x] : 0.f;
        }
        #pragma unroll
        for (int j = 0; j < 4; ++j) {
          int x = x0 + 4 + j;
          ga[i][1][j] = (yok && (unsigned)x < W_) ? rp[x] : 0.f;
        }
      }
    }
  };
  auto writeA = [&](int buf, int h) {
    const int c = h * 4 + cd;
    #pragma unroll
    for (int i = 0; i < 2; ++i) {
      int row = i * 128 + r0;
      bf16x8 t;
      #pragma unroll
      for (int j = 0; j < 4; ++j) {
        t[j]     = (short)__bfloat16_as_ushort(__float2bfloat16(ga[i][0][j]));
        t[4 + j] = (short)__bfloat16_as_ushort(__float2bfloat16(ga[i][1][j]));
      }
      *(bf16x8*)&As[buf][row * 64 + ((c ^ (row & 7)) << 3)] = t;
    }
  };
  auto stageB = [&](int buf, int k0) {
    #pragma unroll
    for (int i = 0; i < 4; ++i) {
      int seg = i * 512 + tid;
      int row = seg >> 3;
      int csrc = (seg & 7) ^ (row & 7);
      const unsigned short* g = Bmat + (size_t)(gn0 + row) * K_N + k0 + csrc * 8;
      __builtin_amdgcn_global_load_lds((const __attribute__((address_space(1))) void*)g,
        (__attribute__((address_space(3))) void*)&Bs[buf][(i * 512 + wave * 64) * 8], 16, 0, 0);
    }
  };

#define MFMA_HALF(BUF, KK) do {                                                  \
    bf16x8 av[8], bv[4];                                                         \
    _Pragma("unroll") for (int mi = 0; mi < 8; ++mi)                             \
      av[mi] = *(const bf16x8*)&As[BUF][(wr * 128 + mi * 16 + rlo) * 64 + swz[KK]]; \
    _Pragma("unroll") for (int ni = 0; ni < 4; ++ni)                             \
      bv[ni] = *(const bf16x8*)&Bs[BUF][(wc * 64 + ni * 16 + rlo) * 64 + swz[KK]];  \
    __builtin_amdgcn_s_setprio(1);                                               \
    _Pragma("unroll") for (int mi = 0; mi < 8; ++mi)                             \
      _Pragma("unroll") for (int ni = 0; ni < 4; ++ni)                           \
        acc[mi][ni] = __builtin_amdgcn_mfma_f32_16x16x32_bf16(                   \
            av[mi], bv[ni], acc[mi][ni], 0, 0, 0);                               \
    __builtin_amdgcn_s_setprio(0);                                               \
  } while (0)

  const int row0 = gm0 + wr * 128 + (lane >> 4) * 4;

  for (int t = 0; t < 3; ++t) {
    gn0 = t * 256;

    // Prologue for this bn-tile: tile 0 fully staged into buf 0.
    // (At t>0: As[0]/Bs[0] last read 2 syncs ago; epilogue stores still in
    // flight are drained by the vmcnt(0) below — correctness-neutral.)
    stageB(0, 0);
    issueA(0, 0); writeA(0, 0);
    issueA(0, 1); writeA(0, 1);
    asm volatile("s_waitcnt vmcnt(0) lgkmcnt(0)" ::: "memory");
    __syncthreads();

    for (int kt = 0; kt < 12; ++kt) {
      const int buf = kt & 1;
      const bool pre = (kt + 1 < 12);
      const int kn = (kt + 1) * 64;

      if (pre) { stageB(buf ^ 1, kn); issueA(kn, 0); }
      MFMA_HALF(buf, 0);
      if (pre) { writeA(buf ^ 1, 0); issueA(kn, 1); }
      MFMA_HALF(buf, 1);
      if (pre) writeA(buf ^ 1, 1);
      asm volatile("s_waitcnt vmcnt(0) lgkmcnt(0)" ::: "memory");
      __syncthreads();
    }

    // Epilogue for this bn-tile: store + reset acc (register-only reads —
    // overlaps the next t's prologue, no barrier needed).
    const int col0 = gn0 + wc * 64 + (lane & 15);
    #pragma unroll
    for (int mi = 0; mi < 8; ++mi)
      #pragma unroll
      for (int ni = 0; ni < 4; ++ni) {
        #pragma unroll
        for (int r = 0; r < 4; ++r)
          out[(size_t)(row0 + mi * 16 + r) * E_N + (col0 + ni * 16)] = acc[mi][ni][r];
        acc[mi][ni] = (f32x4){0.f, 0.f, 0.f, 0.f};
      }
  }
#undef MFMA_HALF
}

extern "C" void kernel_launch(void* const* d_in, const int* in_sizes, int n_in,
                              void* d_out, int out_size, void* d_ws, size_t ws_size,
                              hipStream_t stream) {
  const float* img = (const float*)d_in[0];
  const int*   seg = (const int*)d_in[1];
  const float* cw  = (const float*)d_in[2];
  float* out = (float*)d_out;
  char* ws = (char*)d_ws;

  unsigned long long* partials = (unsigned long long*)ws;    // 8,388,608 B
  unsigned short* Bmat = (unsigned short*)(ws + 8388608);    // 1,179,648 B

  k_accum_convw<<<1600, 256, 0, stream>>>(seg, partials, cw, Bmat);
  k_gemmfg3p<<<256, 512, 0, stream>>>(img, partials, Bmat, out);
}

// Round 22
// 140.703 us; speedup vs baseline: 1.2785x; 1.1926x over previous
//
#include <hip/hip_runtime.h>
#include <hip/hip_bf16.h>
#include <stdint.h>

// Problem constants (fixed by setup_inputs)
#define B_   64
#define H_   512
#define W_   512
#define S_N  1024      // n_segments
#define E_N  768       // embed_dim
#define K_N  768       // C*box*box = 3*16*16
#define HALF 8

typedef short bf16x8 __attribute__((ext_vector_type(8)));
typedef float f32x4  __attribute__((ext_vector_type(4)));
typedef float f32x4u __attribute__((ext_vector_type(4), aligned(4)));  // 4B-aligned float4

__device__ __forceinline__ unsigned short f2bf(float f) {
  union { float f; unsigned u; } v; v.f = f;
  unsigned u = v.u;
  u += 0x7FFF + ((u >> 16) & 1);   // RNE
  return (unsigned short)(u >> 16);
}

// ------ Phase 1 (merged): per-(b,s) packed sums (blocks 0..1023) +
//        conv_w fp32->bf16 (blocks 1024..1599) ---------------------------------
// r21 change: 2-way LDS sub-histograms (tid>>7 picks copy) halve the serialized
// same-address u64-atomic contention; final write sums both copies (exact).
__global__ void k_accum_convw(const int* __restrict__ seg,
                              unsigned long long* __restrict__ partials,
                              const float* __restrict__ w,
                              unsigned short* __restrict__ wb) {
  __shared__ unsigned long long ls[2][S_N];
  const int bid = blockIdx.x;
  const int tid = threadIdx.x;
  if (bid >= 1024) {                 // conv_w conversion: 147,456 float4s
    int idx = (bid - 1024) * 256 + tid;
    float4 v = ((const float4*)w)[idx];
    ushort4 o;
    o.x = f2bf(v.x); o.y = f2bf(v.y); o.z = f2bf(v.z); o.w = f2bf(v.w);
    ((ushort4*)wb)[idx] = o;
    return;
  }
  const int xblk = bid & 15;         // 0..15
  const int b    = bid >> 4;         // 0..63
  for (int i = tid; i < 2 * S_N; i += 256) ls[i >> 10][i & (S_N - 1)] = 0ULL;
  __syncthreads();
  const int hsel = tid >> 7;         // 0 or 1: which sub-histogram
  const int pix0 = xblk * 16384;
  const int4* segb = (const int4*)(seg + (size_t)b * (H_ * W_) + pix0);
  for (int it = 0; it < 16; ++it) {
    int4 s4 = segb[it * 256 + tid];
    int p0 = pix0 + (it * 256 + tid) * 4;
    unsigned long long base = ((unsigned long long)(unsigned)(p0 >> 9) << 39)
                            | ((unsigned long long)(unsigned)(p0 & (W_ - 1)) << 15)
                            | 1ULL;
    #pragma unroll
    for (int j = 0; j < 4; ++j) {
      int s = (&s4.x)[j];
      s = ((unsigned)s < S_N) ? s : 0;
      atomicAdd(&ls[hsel][s], base + ((unsigned long long)j << 15));
    }
  }
  __syncthreads();
  unsigned long long* gp = partials + ((size_t)b * 16 + xblk) * S_N;
  for (int s = tid; s < S_N; s += 256) gp[s] = ls[0][s] + ls[1][s];
}

// ------ Phase 2: FUSED gather-GEMM, dbuf LDS + 16-reg half-tile A prefetch ----
// (r19 kernel, byte-identical — best measured: 141.0us total.)
__global__ __launch_bounds__(512) void k_gemmfg3(
    const float* __restrict__ img,
    const unsigned long long* __restrict__ partials,
    const unsigned short* __restrict__ Bmat,
    float* __restrict__ out) {
  __shared__ unsigned short As[2][256 * 64];   // 2 x 32 KB
  __shared__ unsigned short Bs[2][256 * 64];   // 2 x 32 KB
  __shared__ int2 pc[256];
  const int tid  = threadIdx.x;
  const int wave = tid >> 6;
  const int lane = tid & 63;

  // bijective XCD remap: 768 blocks = 8 XCDs x 96; bn fastest
  const int virt = (blockIdx.x & 7) * 96 + (blockIdx.x >> 3);
  const int bm = virt / 3;
  const int bn = virt - bm * 3;
  const int gm0 = bm * 256;
  const int gn0 = bn * 256;
  const int b   = bm >> 2;
  const float* ib = img + (size_t)b * 3 * H_ * W_;

  // ---- one-time: coords for this block's 256 patches ----
  if (tid < 256) {
    const int s = (gm0 + tid) & (S_N - 1);
    unsigned c = 0, sx = 0, sy = 0;
    #pragma unroll
    for (int x = 0; x < 16; ++x) {
      unsigned long long v = partials[((size_t)b * 16 + x) * S_N + s];
      c  += (unsigned)(v & 0x7FFFULL);
      sx += (unsigned)((v >> 15) & 0xFFFFFFULL);
      sy += (unsigned)(v >> 39);
    }
    int xmin = 0, ymin = 0;
    if (c > 0) {
      float cf = (float)c;
      xmin = (int)floorf((float)sx / cf);   // IEEE f32 div of exact ints == ref
      ymin = (int)floorf((float)sy / cf);
    }
    pc[tid] = make_int2(xmin - HALF, ymin - HALF);
  }

  const int wr = wave >> 2;          // 0..1
  const int wc = wave & 3;           // 0..3
  const int rlo  = lane & 15;
  const int rsel = lane & 7;
  const int sub  = lane >> 4;
  int swz[2];
  swz[0] = ((0 + sub) ^ rsel) * 8;
  swz[1] = ((4 + sub) ^ rsel) * 8;

  f32x4 acc[8][4];
  #pragma unroll
  for (int i = 0; i < 8; ++i)
    #pragma unroll
    for (int j = 0; j < 4; ++j)
      acc[i][j] = (f32x4){0.f, 0.f, 0.f, 0.f};

  __syncthreads();                   // pc ready

  // ---- loop-invariant A-gather context: 2 rows/thread, 4 threads/row ----
  const int cd = tid & 3;
  const int r0 = tid >> 2;           // rows r0 and 128+r0
  int2 pi[2]; bool inti[2];
  const float* arow[2];
  #pragma unroll
  for (int i = 0; i < 2; ++i) {
    int row = i * 128 + r0;
    int2 p = pc[row];
    pi[i] = p;
    inti[i] = (p.x >= 0 && p.x <= W_ - 16 && p.y >= 0 && p.y <= H_ - 16);
    arow[i] = ib + (size_t)(inti[i] ? p.y : 0) * W_ + (inti[i] ? p.x : 0);
  }

  f32x4 ga[2][2];                    // 16 VGPRs live across one MFMA sub-phase

  auto issueA = [&](int k0, int h) {
    const int c  = h * 4 + cd;
    const int k  = k0 + c * 8;
    const int ch = k >> 8, hh = (k >> 4) & 15, w0 = k & 15;
    const int roff = ((ch << 9) + hh) * W_ + w0;
    #pragma unroll
    for (int i = 0; i < 2; ++i) {
      if (inti[i]) {
        const float* rp = arow[i] + roff;
        ga[i][0] = *(const f32x4u*)rp;
        ga[i][1] = *(const f32x4u*)(rp + 4);
      } else {
        int y = pi[i].y + hh;
        int x0 = pi[i].x + w0;
        bool yok = (unsigned)y < H_;
        const float* rp = ib + (size_t)((ch << 9) + (yok ? y : 0)) * W_;
        #pragma unroll
        for (int j = 0; j < 4; ++j) {
          int x = x0 + j;
          ga[i][0][j] = (yok && (unsigned)x < W_) ? rp[x] : 0.f;
        }
        #pragma unroll
        for (int j = 0; j < 4; ++j) {
          int x = x0 + 4 + j;
          ga[i][1][j] = (yok && (unsigned)x < W_) ? rp[x] : 0.f;
        }
      }
    }
  };
  auto writeA = [&](int buf, int h) {
    const int c = h * 4 + cd;
    #pragma unroll
    for (int i = 0; i < 2; ++i) {
      int row = i * 128 + r0;
      bf16x8 t;
      #pragma unroll
      for (int j = 0; j < 4; ++j) {
        t[j]     = (short)__bfloat16_as_ushort(__float2bfloat16(ga[i][0][j]));
        t[4 + j] = (short)__bfloat16_as_ushort(__float2bfloat16(ga[i][1][j]));
      }
      *(bf16x8*)&As[buf][row * 64 + ((c ^ (row & 7)) << 3)] = t;
    }
  };
  auto stageB = [&](int buf, int k0) {
    #pragma unroll
    for (int i = 0; i < 4; ++i) {
      int seg = i * 512 + tid;
      int row = seg >> 3;
      int csrc = (seg & 7) ^ (row & 7);
      const unsigned short* g = Bmat + (size_t)(gn0 + row) * K_N + k0 + csrc * 8;
      __builtin_amdgcn_global_load_lds((const __attribute__((address_space(1))) void*)g,
        (__attribute__((address_space(3))) void*)&Bs[buf][(i * 512 + wave * 64) * 8], 16, 0, 0);
    }
  };

#define MFMA_HALF(BUF, KK) do {                                                  \
    bf16x8 av[8], bv[4];                                                         \
    _Pragma("unroll") for (int mi = 0; mi < 8; ++mi)                             \
      av[mi] = *(const bf16x8*)&As[BUF][(wr * 128 + mi * 16 + rlo) * 64 + swz[KK]]; \
    _Pragma("unroll") for (int ni = 0; ni < 4; ++ni)                             \
      bv[ni] = *(const bf16x8*)&Bs[BUF][(wc * 64 + ni * 16 + rlo) * 64 + swz[KK]];  \
    __builtin_amdgcn_s_setprio(1);                                               \
    _Pragma("unroll") for (int mi = 0; mi < 8; ++mi)                             \
      _Pragma("unroll") for (int ni = 0; ni < 4; ++ni)                           \
        acc[mi][ni] = __builtin_amdgcn_mfma_f32_16x16x32_bf16(                   \
            av[mi], bv[ni], acc[mi][ni], 0, 0, 0);                               \
    __builtin_amdgcn_s_setprio(0);                                               \
  } while (0)

  // Prologue: tile 0 fully staged into buf 0.
  stageB(0, 0);
  issueA(0, 0); writeA(0, 0);
  issueA(0, 1); writeA(0, 1);
  asm volatile("s_waitcnt vmcnt(0) lgkmcnt(0)" ::: "memory");
  __syncthreads();

  for (int kt = 0; kt < 12; ++kt) {
    const int buf = kt & 1;
    const bool pre = (kt + 1 < 12);
    const int kn = (kt + 1) * 64;

    if (pre) { stageB(buf ^ 1, kn); issueA(kn, 0); }   // no-reg B, 16-reg A
    MFMA_HALF(buf, 0);                                 // half0 latency hides
    if (pre) { writeA(buf ^ 1, 0); issueA(kn, 1); }
    MFMA_HALF(buf, 1);                                 // half1 hides
    if (pre) writeA(buf ^ 1, 1);
    asm volatile("s_waitcnt vmcnt(0) lgkmcnt(0)" ::: "memory");
    __syncthreads();                                   // single publish barrier
  }

  // Epilogue: C/D layout col=lane&15, row=(lane>>4)*4+reg
  const int row0 = gm0 + wr * 128 + (lane >> 4) * 4;
  const int col0 = gn0 + wc * 64 + (lane & 15);
  #pragma unroll
  for (int mi = 0; mi < 8; ++mi)
    #pragma unroll
    for (int ni = 0; ni < 4; ++ni)
      #pragma unroll
      for (int r = 0; r < 4; ++r)
        out[(size_t)(row0 + mi * 16 + r) * E_N + (col0 + ni * 16)] = acc[mi][ni][r];
#undef MFMA_HALF
}

extern "C" void kernel_launch(void* const* d_in, const int* in_sizes, int n_in,
                              void* d_out, int out_size, void* d_ws, size_t ws_size,
                              hipStream_t stream) {
  const float* img = (const float*)d_in[0];
  const int*   seg = (const int*)d_in[1];
  const float* cw  = (const float*)d_in[2];
  float* out = (float*)d_out;
  char* ws = (char*)d_ws;

  unsigned long long* partials = (unsigned long long*)ws;    // 8,388,608 B
  unsigned short* Bmat = (unsigned short*)(ws + 8388608);    // 1,179,648 B

  k_accum_convw<<<1600, 256, 0, stream>>>(seg, partials, cw, Bmat);
  k_gemmfg3<<<768, 512, 0, stream>>>(img, partials, Bmat, out);
}

// Round 23
// 140.002 us; speedup vs baseline: 1.2849x; 1.0050x over previous
//
#include <hip/hip_runtime.h>
#include <hip/hip_bf16.h>
#include <stdint.h>

// ============================================================================
// DifferentiableSuperpixelTokenizer — FINAL (session best: 140.7 us)
// Pipeline: (1) k_accum_convw — per-(b,s) packed integer centroid sums via
// 2-way LDS u64 sub-histograms (bit-exact vs reference f32 scatter-add, all
// sums < 2^24) + conv_w fp32->bf16; (2) k_gemmfg3 — fused coalesced patch
// gather + 256x256 bf16 MFMA GEMM, dbuf LDS, 16-reg half-tile A prefetch
// (T14), T2 both-sides XOR swizzle, bijective XCD remap.
// Key measured facts: FETCH 21 MB (img center L2-resident), WRITE 197 MB
// (= output, no spill), absmax 0.0156 (bf16 floor), GEMM = 93% of runtime,
// register budget (acc 128 AGPR) pins occupancy at 1 block/CU.
// ============================================================================

// Problem constants (fixed by setup_inputs)
#define B_   64
#define H_   512
#define W_   512
#define S_N  1024      // n_segments
#define E_N  768       // embed_dim
#define K_N  768       // C*box*box = 3*16*16
#define HALF 8

typedef short bf16x8 __attribute__((ext_vector_type(8)));
typedef float f32x4  __attribute__((ext_vector_type(4)));
typedef float f32x4u __attribute__((ext_vector_type(4), aligned(4)));  // 4B-aligned float4

__device__ __forceinline__ unsigned short f2bf(float f) {
  union { float f; unsigned u; } v; v.f = f;
  unsigned u = v.u;
  u += 0x7FFF + ((u >> 16) & 1);   // RNE
  return (unsigned short)(u >> 16);
}

// ------ Phase 1 (merged): per-(b,s) packed sums (blocks 0..1023) +
//        conv_w fp32->bf16 (blocks 1024..1599) ---------------------------------
__global__ void k_accum_convw(const int* __restrict__ seg,
                              unsigned long long* __restrict__ partials,
                              const float* __restrict__ w,
                              unsigned short* __restrict__ wb) {
  __shared__ unsigned long long ls[2][S_N];
  const int bid = blockIdx.x;
  const int tid = threadIdx.x;
  if (bid >= 1024) {                 // conv_w conversion: 147,456 float4s
    int idx = (bid - 1024) * 256 + tid;
    float4 v = ((const float4*)w)[idx];
    ushort4 o;
    o.x = f2bf(v.x); o.y = f2bf(v.y); o.z = f2bf(v.z); o.w = f2bf(v.w);
    ((ushort4*)wb)[idx] = o;
    return;
  }
  const int xblk = bid & 15;         // 0..15
  const int b    = bid >> 4;         // 0..63
  for (int i = tid; i < 2 * S_N; i += 256) ls[i >> 10][i & (S_N - 1)] = 0ULL;
  __syncthreads();
  const int hsel = tid >> 7;         // 0 or 1: which sub-histogram
  const int pix0 = xblk * 16384;
  const int4* segb = (const int4*)(seg + (size_t)b * (H_ * W_) + pix0);
  for (int it = 0; it < 16; ++it) {
    int4 s4 = segb[it * 256 + tid];
    int p0 = pix0 + (it * 256 + tid) * 4;
    unsigned long long base = ((unsigned long long)(unsigned)(p0 >> 9) << 39)
                            | ((unsigned long long)(unsigned)(p0 & (W_ - 1)) << 15)
                            | 1ULL;
    #pragma unroll
    for (int j = 0; j < 4; ++j) {
      int s = (&s4.x)[j];
      s = ((unsigned)s < S_N) ? s : 0;
      atomicAdd(&ls[hsel][s], base + ((unsigned long long)j << 15));
    }
  }
  __syncthreads();
  unsigned long long* gp = partials + ((size_t)b * 16 + xblk) * S_N;
  for (int s = tid; s < S_N; s += 256) gp[s] = ls[0][s] + ls[1][s];
}

// ------ Phase 2: FUSED gather-GEMM, dbuf LDS + 16-reg half-tile A prefetch ----
__global__ __launch_bounds__(512) void k_gemmfg3(
    const float* __restrict__ img,
    const unsigned long long* __restrict__ partials,
    const unsigned short* __restrict__ Bmat,
    float* __restrict__ out) {
  __shared__ unsigned short As[2][256 * 64];   // 2 x 32 KB
  __shared__ unsigned short Bs[2][256 * 64];   // 2 x 32 KB
  __shared__ int2 pc[256];
  const int tid  = threadIdx.x;
  const int wave = tid >> 6;
  const int lane = tid & 63;

  // bijective XCD remap: 768 blocks = 8 XCDs x 96; bn fastest
  const int virt = (blockIdx.x & 7) * 96 + (blockIdx.x >> 3);
  const int bm = virt / 3;
  const int bn = virt - bm * 3;
  const int gm0 = bm * 256;
  const int gn0 = bn * 256;
  const int b   = bm >> 2;
  const float* ib = img + (size_t)b * 3 * H_ * W_;

  // ---- one-time: coords for this block's 256 patches ----
  if (tid < 256) {
    const int s = (gm0 + tid) & (S_N - 1);
    unsigned c = 0, sx = 0, sy = 0;
    #pragma unroll
    for (int x = 0; x < 16; ++x) {
      unsigned long long v = partials[((size_t)b * 16 + x) * S_N + s];
      c  += (unsigned)(v & 0x7FFFULL);
      sx += (unsigned)((v >> 15) & 0xFFFFFFULL);
      sy += (unsigned)(v >> 39);
    }
    int xmin = 0, ymin = 0;
    if (c > 0) {
      float cf = (float)c;
      xmin = (int)floorf((float)sx / cf);   // IEEE f32 div of exact ints == ref
      ymin = (int)floorf((float)sy / cf);
    }
    pc[tid] = make_int2(xmin - HALF, ymin - HALF);
  }

  const int wr = wave >> 2;          // 0..1
  const int wc = wave & 3;           // 0..3
  const int rlo  = lane & 15;
  const int rsel = lane & 7;
  const int sub  = lane >> 4;
  int swz[2];
  swz[0] = ((0 + sub) ^ rsel) * 8;
  swz[1] = ((4 + sub) ^ rsel) * 8;

  f32x4 acc[8][4];
  #pragma unroll
  for (int i = 0; i < 8; ++i)
    #pragma unroll
    for (int j = 0; j < 4; ++j)
      acc[i][j] = (f32x4){0.f, 0.f, 0.f, 0.f};

  __syncthreads();                   // pc ready

  // ---- loop-invariant A-gather context: 2 rows/thread, 4 threads/row ----
  const int cd = tid & 3;
  const int r0 = tid >> 2;           // rows r0 and 128+r0
  int2 pi[2]; bool inti[2];
  const float* arow[2];
  #pragma unroll
  for (int i = 0; i < 2; ++i) {
    int row = i * 128 + r0;
    int2 p = pc[row];
    pi[i] = p;
    inti[i] = (p.x >= 0 && p.x <= W_ - 16 && p.y >= 0 && p.y <= H_ - 16);
    arow[i] = ib + (size_t)(inti[i] ? p.y : 0) * W_ + (inti[i] ? p.x : 0);
  }

  f32x4 ga[2][2];                    // 16 VGPRs live across one MFMA sub-phase

  auto issueA = [&](int k0, int h) {
    const int c  = h * 4 + cd;
    const int k  = k0 + c * 8;
    const int ch = k >> 8, hh = (k >> 4) & 15, w0 = k & 15;
    const int roff = ((ch << 9) + hh) * W_ + w0;
    #pragma unroll
    for (int i = 0; i < 2; ++i) {
      if (inti[i]) {
        const float* rp = arow[i] + roff;
        ga[i][0] = *(const f32x4u*)rp;
        ga[i][1] = *(const f32x4u*)(rp + 4);
      } else {
        int y = pi[i].y + hh;
        int x0 = pi[i].x + w0;
        bool yok = (unsigned)y < H_;
        const float* rp = ib + (size_t)((ch << 9) + (yok ? y : 0)) * W_;
        #pragma unroll
        for (int j = 0; j < 4; ++j) {
          int x = x0 + j;
          ga[i][0][j] = (yok && (unsigned)x < W_) ? rp[x] : 0.f;
        }
        #pragma unroll
        for (int j = 0; j < 4; ++j) {
          int x = x0 + 4 + j;
          ga[i][1][j] = (yok && (unsigned)x < W_) ? rp[x] : 0.f;
        }
      }
    }
  };
  auto writeA = [&](int buf, int h) {
    const int c = h * 4 + cd;
    #pragma unroll
    for (int i = 0; i < 2; ++i) {
      int row = i * 128 + r0;
      bf16x8 t;
      #pragma unroll
      for (int j = 0; j < 4; ++j) {
        t[j]     = (short)__bfloat16_as_ushort(__float2bfloat16(ga[i][0][j]));
        t[4 + j] = (short)__bfloat16_as_ushort(__float2bfloat16(ga[i][1][j]));
      }
      *(bf16x8*)&As[buf][row * 64 + ((c ^ (row & 7)) << 3)] = t;
    }
  };
  auto stageB = [&](int buf, int k0) {
    #pragma unroll
    for (int i = 0; i < 4; ++i) {
      int seg = i * 512 + tid;
      int row = seg >> 3;
      int csrc = (seg & 7) ^ (row & 7);
      const unsigned short* g = Bmat + (size_t)(gn0 + row) * K_N + k0 + csrc * 8;
      __builtin_amdgcn_global_load_lds((const __attribute__((address_space(1))) void*)g,
        (__attribute__((address_space(3))) void*)&Bs[buf][(i * 512 + wave * 64) * 8], 16, 0, 0);
    }
  };

#define MFMA_HALF(BUF, KK) do {                                                  \
    bf16x8 av[8], bv[4];                                                         \
    _Pragma("unroll") for (int mi = 0; mi < 8; ++mi)                             \
      av[mi] = *(const bf16x8*)&As[BUF][(wr * 128 + mi * 16 + rlo) * 64 + swz[KK]]; \
    _Pragma("unroll") for (int ni = 0; ni < 4; ++ni)                             \
      bv[ni] = *(const bf16x8*)&Bs[BUF][(wc * 64 + ni * 16 + rlo) * 64 + swz[KK]];  \
    __builtin_amdgcn_s_setprio(1);                                               \
    _Pragma("unroll") for (int mi = 0; mi < 8; ++mi)                             \
      _Pragma("unroll") for (int ni = 0; ni < 4; ++ni)                           \
        acc[mi][ni] = __builtin_amdgcn_mfma_f32_16x16x32_bf16(                   \
            av[mi], bv[ni], acc[mi][ni], 0, 0, 0);                               \
    __builtin_amdgcn_s_setprio(0);                                               \
  } while (0)

  // Prologue: tile 0 fully staged into buf 0.
  stageB(0, 0);
  issueA(0, 0); writeA(0, 0);
  issueA(0, 1); writeA(0, 1);
  asm volatile("s_waitcnt vmcnt(0) lgkmcnt(0)" ::: "memory");
  __syncthreads();

  for (int kt = 0; kt < 12; ++kt) {
    const int buf = kt & 1;
    const bool pre = (kt + 1 < 12);
    const int kn = (kt + 1) * 64;

    if (pre) { stageB(buf ^ 1, kn); issueA(kn, 0); }   // no-reg B, 16-reg A
    MFMA_HALF(buf, 0);                                 // half0 latency hides
    if (pre) { writeA(buf ^ 1, 0); issueA(kn, 1); }
    MFMA_HALF(buf, 1);                                 // half1 hides
    if (pre) writeA(buf ^ 1, 1);
    asm volatile("s_waitcnt vmcnt(0) lgkmcnt(0)" ::: "memory");
    __syncthreads();                                   // single publish barrier
  }

  // Epilogue: C/D layout col=lane&15, row=(lane>>4)*4+reg
  const int row0 = gm0 + wr * 128 + (lane >> 4) * 4;
  const int col0 = gn0 + wc * 64 + (lane & 15);
  #pragma unroll
  for (int mi = 0; mi < 8; ++mi)
    #pragma unroll
    for (int ni = 0; ni < 4; ++ni)
      #pragma unroll
      for (int r = 0; r < 4; ++r)
        out[(size_t)(row0 + mi * 16 + r) * E_N + (col0 + ni * 16)] = acc[mi][ni][r];
#undef MFMA_HALF
}

extern "C" void kernel_launch(void* const* d_in, const int* in_sizes, int n_in,
                              void* d_out, int out_size, void* d_ws, size_t ws_size,
                              hipStream_t stream) {
  const float* img = (const float*)d_in[0];
  const int*   seg = (const int*)d_in[1];
  const float* cw  = (const float*)d_in[2];
  float* out = (float*)d_out;
  char* ws = (char*)d_ws;

  unsigned long long* partials = (unsigned long long*)ws;    // 8,388,608 B
  unsigned short* Bmat = (unsigned short*)(ws + 8388608);    // 1,179,648 B

  k_accum_convw<<<1600, 256, 0, stream>>>(seg, partials, cw, Bmat);
  k_gemmfg3<<<768, 512, 0, stream>>>(img, partials, Bmat, out);
}